// Round 13
// baseline (322.383 us; speedup 1.0000x reference)
//
#include <hip/hip_runtime.h>
#include <stdint.h>

#define NS 150
#define D_IN 1024
#define D_H 512
#define D_OUT 256

typedef __bf16 bf16x8 __attribute__((ext_vector_type(8)));
typedef float f32x4 __attribute__((ext_vector_type(4)));

// ---- workspace layout (float offsets) ----
#define OFF_XF    0u          // x fragments, 32768 bf16 (MFMA B-operand order)
#define OFF_MS1T  16384u      // float2[512*1024] (mu,std) at [h][i]
#define OFF_MS2T  1064960u    // float2[256*512]  (mu,std) at [o][h]
#define OFF_B1S   1327104u    // 150*512 = 76800
#define OFF_B2S   1403904u    // 150*256 = 38400
#define OFF_HB    1442304u    // h bf16 [n][b][h]: 150*32*512 bf16

// sqrt(2)-folded ErfInv coefficients
#define SQ2 1.41421354f
#define CM0 (SQ2 * 2.81022636e-08f)
#define CM1 (SQ2 * 3.43273939e-07f)
#define CM2 (SQ2 * -3.5233877e-06f)
#define CM3 (SQ2 * -4.39150654e-06f)
#define CM4 (SQ2 * 0.00021858087f)
#define CM5 (SQ2 * -0.00125372503f)
#define CM6 (SQ2 * -0.00417768164f)
#define CM7 (SQ2 * 0.246640727f)
#define CM8 (SQ2 * 1.50140941f)
#define CT0 (SQ2 * -0.000200214257f)
#define CT1 (SQ2 * 0.000100950558f)
#define CT2 (SQ2 * 0.00134934322f)
#define CT3 (SQ2 * -0.00367342844f)
#define CT4 (SQ2 * 0.00573950773f)
#define CT5 (SQ2 * -0.0076224613f)
#define CT6 (SQ2 * 0.00943887047f)
#define CT7 (SQ2 * 1.00167406f)
#define CT8 (SQ2 * 2.83297682f)

// ---------- threefry-2x32 (JAX-exact, 20 rounds) ----------
#define ROTL32(x, r) __builtin_rotateleft32((x), (r))

__host__ __device__ __forceinline__ void threefry2x32(uint32_t k0, uint32_t k1,
                                                      uint32_t x0, uint32_t x1,
                                                      uint32_t& o0, uint32_t& o1) {
  uint32_t k2 = k0 ^ k1 ^ 0x1BD11BDAu;
  x0 += k0; x1 += k1;
#define TFR(r) { x0 += x1; x1 = ROTL32(x1, r); x1 ^= x0; }
  TFR(13) TFR(15) TFR(26) TFR(6)
  x0 += k1; x1 += k2 + 1u;
  TFR(17) TFR(29) TFR(16) TFR(24)
  x0 += k2; x1 += k0 + 2u;
  TFR(13) TFR(15) TFR(26) TFR(6)
  x0 += k0; x1 += k1 + 3u;
  TFR(17) TFR(29) TFR(16) TFR(24)
  x0 += k1; x1 += k2 + 4u;
  TFR(13) TFR(15) TFR(26) TFR(6)
  x0 += k2; x1 += k0 + 5u;
#undef TFR
  o0 = x0; o1 = x1;
}

// scalar path (prep biases only)
__device__ __forceinline__ float tf_normal(uint32_t k0, uint32_t k1, uint32_t idx) {
  uint32_t o0, o1;
  threefry2x32(k0, k1, 0u, idx, o0, o1);
  uint32_t bits = o0 ^ o1;
  uint32_t fb = (bits >> 9) | 0x3F800000u;
  float m = __uint_as_float(fb);
  const float lo = -0.99999994f;
  float u = fmaxf(fmaf(m, 2.0f, -3.0f), lo);
  float t = fmaf(u, -u, 1.0f);
  float w = -0.69314718056f * __builtin_amdgcn_logf(t);
  float p;
  if (w < 5.0f) {
    float ww = w - 2.5f;
    p = CM0;
    p = fmaf(p, ww, CM1); p = fmaf(p, ww, CM2); p = fmaf(p, ww, CM3);
    p = fmaf(p, ww, CM4); p = fmaf(p, ww, CM5); p = fmaf(p, ww, CM6);
    p = fmaf(p, ww, CM7); p = fmaf(p, ww, CM8);
  } else {
    float ww = __builtin_amdgcn_sqrtf(w) - 3.0f;
    p = CT0;
    p = fmaf(p, ww, CT1); p = fmaf(p, ww, CT2); p = fmaf(p, ww, CT3);
    p = fmaf(p, ww, CT4); p = fmaf(p, ww, CT5); p = fmaf(p, ww, CT6);
    p = fmaf(p, ww, CT7); p = fmaf(p, ww, CT8);
  }
  return p * u;
}

// ---------- 8-chain threefry: INLINE ASM (R12, proven: 248->206us) ----------
#define TF_ADD8 \
  "v_add_u32 %[a0], %[a0], %[b0]\n\t" "v_add_u32 %[a1], %[a1], %[b1]\n\t" \
  "v_add_u32 %[a2], %[a2], %[b2]\n\t" "v_add_u32 %[a3], %[a3], %[b3]\n\t" \
  "v_add_u32 %[a4], %[a4], %[b4]\n\t" "v_add_u32 %[a5], %[a5], %[b5]\n\t" \
  "v_add_u32 %[a6], %[a6], %[b6]\n\t" "v_add_u32 %[a7], %[a7], %[b7]\n\t"
#define TF_ROT8(sh) \
  "v_alignbit_b32 %[b0], %[b0], %[b0], " sh "\n\t" \
  "v_alignbit_b32 %[b1], %[b1], %[b1], " sh "\n\t" \
  "v_alignbit_b32 %[b2], %[b2], %[b2], " sh "\n\t" \
  "v_alignbit_b32 %[b3], %[b3], %[b3], " sh "\n\t" \
  "v_alignbit_b32 %[b4], %[b4], %[b4], " sh "\n\t" \
  "v_alignbit_b32 %[b5], %[b5], %[b5], " sh "\n\t" \
  "v_alignbit_b32 %[b6], %[b6], %[b6], " sh "\n\t" \
  "v_alignbit_b32 %[b7], %[b7], %[b7], " sh "\n\t"
#define TF_XOR8 \
  "v_xor_b32 %[b0], %[b0], %[a0]\n\t" "v_xor_b32 %[b1], %[b1], %[a1]\n\t" \
  "v_xor_b32 %[b2], %[b2], %[a2]\n\t" "v_xor_b32 %[b3], %[b3], %[a3]\n\t" \
  "v_xor_b32 %[b4], %[b4], %[a4]\n\t" "v_xor_b32 %[b5], %[b5], %[a5]\n\t" \
  "v_xor_b32 %[b6], %[b6], %[a6]\n\t" "v_xor_b32 %[b7], %[b7], %[a7]\n\t"
#define TF_ROUND(sh) TF_ADD8 TF_ROT8(sh) TF_XOR8
#define TF_INJ(KA, KB) \
  "v_add_u32 %[a0], " KA ", %[a0]\n\t" "v_add_u32 %[a1], " KA ", %[a1]\n\t" \
  "v_add_u32 %[a2], " KA ", %[a2]\n\t" "v_add_u32 %[a3], " KA ", %[a3]\n\t" \
  "v_add_u32 %[a4], " KA ", %[a4]\n\t" "v_add_u32 %[a5], " KA ", %[a5]\n\t" \
  "v_add_u32 %[a6], " KA ", %[a6]\n\t" "v_add_u32 %[a7], " KA ", %[a7]\n\t" \
  "v_add_u32 %[b0], " KB ", %[b0]\n\t" "v_add_u32 %[b1], " KB ", %[b1]\n\t" \
  "v_add_u32 %[b2], " KB ", %[b2]\n\t" "v_add_u32 %[b3], " KB ", %[b3]\n\t" \
  "v_add_u32 %[b4], " KB ", %[b4]\n\t" "v_add_u32 %[b5], " KB ", %[b5]\n\t" \
  "v_add_u32 %[b6], " KB ", %[b6]\n\t" "v_add_u32 %[b7], " KB ", %[b7]\n\t"

__device__ __forceinline__ void tf8_bits(uint32_t k0, uint32_t k1, uint32_t k2,
                                         uint32_t idx0, uint32_t* bits) {
  uint32_t k2p1 = k2 + 1u, k0p2 = k0 + 2u, k1p3 = k1 + 3u;
  uint32_t k2p4 = k2 + 4u, k0p5 = k0 + 5u;
  uint32_t t0 = idx0 + k1;
  uint32_t a0 = k0, a1 = k0, a2 = k0, a3 = k0, a4 = k0, a5 = k0, a6 = k0, a7 = k0;
  uint32_t b0 = t0, b1 = t0 + 1u, b2 = t0 + 2u, b3 = t0 + 3u;
  uint32_t b4 = t0 + 4u, b5 = t0 + 5u, b6 = t0 + 6u, b7 = t0 + 7u;
  asm(TF_ROUND("19") TF_ROUND("17") TF_ROUND("6") TF_ROUND("26")
      TF_INJ("%[k1]", "%[k2p1]")
      TF_ROUND("15") TF_ROUND("3") TF_ROUND("16") TF_ROUND("8")
      TF_INJ("%[k2]", "%[k0p2]")
      TF_ROUND("19") TF_ROUND("17") TF_ROUND("6") TF_ROUND("26")
      TF_INJ("%[k0]", "%[k1p3]")
      TF_ROUND("15") TF_ROUND("3") TF_ROUND("16") TF_ROUND("8")
      TF_INJ("%[k1]", "%[k2p4]")
      TF_ROUND("19") TF_ROUND("17") TF_ROUND("6") TF_ROUND("26")
      TF_INJ("%[k2]", "%[k0p5]")
      : [a0]"+v"(a0), [a1]"+v"(a1), [a2]"+v"(a2), [a3]"+v"(a3),
        [a4]"+v"(a4), [a5]"+v"(a5), [a6]"+v"(a6), [a7]"+v"(a7),
        [b0]"+v"(b0), [b1]"+v"(b1), [b2]"+v"(b2), [b3]"+v"(b3),
        [b4]"+v"(b4), [b5]"+v"(b5), [b6]"+v"(b6), [b7]"+v"(b7)
      : [k0]"s"(k0), [k1]"s"(k1), [k2]"s"(k2), [k2p1]"s"(k2p1),
        [k0p2]"s"(k0p2), [k1p3]"s"(k1p3), [k2p4]"s"(k2p4), [k0p5]"s"(k0p5));
  bits[0] = a0 ^ b0; bits[1] = a1 ^ b1; bits[2] = a2 ^ b2; bits[3] = a3 ^ b3;
  bits[4] = a4 ^ b4; bits[5] = a5 ^ b5; bits[6] = a6 ^ b6; bits[7] = a7 ^ b7;
}

// ---------- transform, hand-scheduled asm, branchless ----------
#define FOR8(M) M(0) M(1) M(2) M(3) M(4) M(5) M(6) M(7)
#define FOR4(M) M(0) M(1) M(2) M(3)

// Block A (8-wide): bits -> u in (-1,1), w = -ln(1-u^2)
#define A_SHR(j) "v_lshrrev_b32 %[u" #j "], 9, %[b" #j "]\n\t"
#define A_OR(j)  "v_or_b32 %[u" #j "], 0x3f800000, %[u" #j "]\n\t"
#define A_FMA(j) "v_fma_f32 %[u" #j "], %[u" #j "], 2.0, %[cm3]\n\t"
#define A_MAX(j) "v_max_f32 %[u" #j "], %[clo], %[u" #j "]\n\t"
#define A_T(j)   "v_fma_f32 %[w" #j "], %[u" #j "], -%[u" #j "], 1.0\n\t"
#define A_LOG(j) "v_log_f32 %[w" #j "], %[w" #j "]\n\t"
#define A_MUL(j) "v_mul_f32 %[w" #j "], %[cln], %[w" #j "]\n\t"

// Block B (4-wide): main-branch Horner, coeffs in SGPRs (1 sgpr/instr: legal)
#define B_ADD(j) "v_add_f32 %[a" #j "], 0xc0200000, %[w" #j "]\n\t"  /* w - 2.5 */
#define B_MOV(j) "v_mov_b32 %[p" #j "], %[c0]\n\t"
#define B_F(j,c) "v_fma_f32 %[p" #j "], %[p" #j "], %[a" #j "], %[c" #c "]\n\t"
#define B_FMA(c) B_F(0,c) B_F(1,c) B_F(2,c) B_F(3,c)

// Block C (4-wide): tail Horner + branchless select + final mul
#define C_SQ(j)  "v_sqrt_f32 %[t" #j "], %[w" #j "]\n\t"
#define C_ADD(j) "v_add_f32 %[t" #j "], 0xc0400000, %[t" #j "]\n\t"  /* sqrt(w)-3 */
#define C_MOV(j) "v_mov_b32 %[q" #j "], %[c0]\n\t"
#define C_F(j,c) "v_fma_f32 %[q" #j "], %[q" #j "], %[t" #j "], %[c" #c "]\n\t"
#define C_FMA(c) C_F(0,c) C_F(1,c) C_F(2,c) C_F(3,c)
#define C_SEL(j) "v_cmp_gt_f32 vcc, 0x40a00000, %[w" #j "]\n\t" \
                 "v_cndmask_b32 %[p" #j "], %[q" #j "], %[p" #j "], vcc\n\t"
#define C_MUL(j) "v_mul_f32 %[p" #j "], %[p" #j "], %[u" #j "]\n\t"

__device__ __forceinline__ void erf4(float w0, float w1, float w2, float w3,
                                     float u0, float u1, float u2, float u3,
                                     float& e0, float& e1, float& e2, float& e3) {
  float a0, a1, a2, a3, p0, p1, p2, p3, t0, t1, t2, t3, q0, q1, q2, q3;
  asm(FOR4(B_ADD) FOR4(B_MOV)
      B_FMA(1) B_FMA(2) B_FMA(3) B_FMA(4) B_FMA(5) B_FMA(6) B_FMA(7) B_FMA(8)
      : [a0]"=&v"(a0), [a1]"=&v"(a1), [a2]"=&v"(a2), [a3]"=&v"(a3),
        [p0]"=&v"(p0), [p1]"=&v"(p1), [p2]"=&v"(p2), [p3]"=&v"(p3)
      : [w0]"v"(w0), [w1]"v"(w1), [w2]"v"(w2), [w3]"v"(w3),
        [c0]"s"(CM0), [c1]"s"(CM1), [c2]"s"(CM2), [c3]"s"(CM3), [c4]"s"(CM4),
        [c5]"s"(CM5), [c6]"s"(CM6), [c7]"s"(CM7), [c8]"s"(CM8));
  asm(FOR4(C_SQ) FOR4(C_ADD) FOR4(C_MOV)
      C_FMA(1) C_FMA(2) C_FMA(3) C_FMA(4) C_FMA(5) C_FMA(6) C_FMA(7) C_FMA(8)
      FOR4(C_SEL) FOR4(C_MUL)
      : [t0]"=&v"(t0), [t1]"=&v"(t1), [t2]"=&v"(t2), [t3]"=&v"(t3),
        [q0]"=&v"(q0), [q1]"=&v"(q1), [q2]"=&v"(q2), [q3]"=&v"(q3),
        [p0]"+v"(p0), [p1]"+v"(p1), [p2]"+v"(p2), [p3]"+v"(p3)
      : [w0]"v"(w0), [w1]"v"(w1), [w2]"v"(w2), [w3]"v"(w3),
        [u0]"v"(u0), [u1]"v"(u1), [u2]"v"(u2), [u3]"v"(u3),
        [c0]"s"(CT0), [c1]"s"(CT1), [c2]"s"(CT2), [c3]"s"(CT3), [c4]"s"(CT4),
        [c5]"s"(CT5), [c6]"s"(CT6), [c7]"s"(CT7), [c8]"s"(CT8)
      : "vcc");
  e0 = p0; e1 = p1; e2 = p2; e3 = p3;
}

__device__ __forceinline__ void tf8_eps(uint32_t k0, uint32_t k1, uint32_t k2,
                                        uint32_t idx0, float* eps) {
  uint32_t bits[8];
  tf8_bits(k0, k1, k2, idx0, bits);
  float u0, u1, u2, u3, u4, u5, u6, u7;
  float w0, w1, w2, w3, w4, w5, w6, w7;
  asm(FOR8(A_SHR) FOR8(A_OR) FOR8(A_FMA) FOR8(A_MAX)
      FOR8(A_T) FOR8(A_LOG) FOR8(A_MUL)
      : [u0]"=&v"(u0), [u1]"=&v"(u1), [u2]"=&v"(u2), [u3]"=&v"(u3),
        [u4]"=&v"(u4), [u5]"=&v"(u5), [u6]"=&v"(u6), [u7]"=&v"(u7),
        [w0]"=&v"(w0), [w1]"=&v"(w1), [w2]"=&v"(w2), [w3]"=&v"(w3),
        [w4]"=&v"(w4), [w5]"=&v"(w5), [w6]"=&v"(w6), [w7]"=&v"(w7)
      : [b0]"v"(bits[0]), [b1]"v"(bits[1]), [b2]"v"(bits[2]), [b3]"v"(bits[3]),
        [b4]"v"(bits[4]), [b5]"v"(bits[5]), [b6]"v"(bits[6]), [b7]"v"(bits[7]),
        [cm3]"s"(-3.0f), [clo]"s"(-0.99999994f), [cln]"s"(-0.69314718056f));
  erf4(w0, w1, w2, w3, u0, u1, u2, u3, eps[0], eps[1], eps[2], eps[3]);
  erf4(w4, w5, w6, w7, u4, u5, u6, u7, eps[4], eps[5], eps[6], eps[7]);
}

// ---------- prep ----------
__global__ __launch_bounds__(256) void prep_kernel(
    const float* __restrict__ x,
    const float* __restrict__ muW1, const float* __restrict__ vW1,
    const float* __restrict__ muW2, const float* __restrict__ vW2,
    const float* __restrict__ mub1, const float* __restrict__ vb1,
    const float* __restrict__ mub2, const float* __restrict__ vb2,
    float* __restrict__ ws,
    uint32_t kb1_0, uint32_t kb1_1, uint32_t kb2_0, uint32_t kb2_1) {
  int bb = blockIdx.x;
  int tid = threadIdx.x;
  if (bb < 2048) {
    int t = bb * 256 + tid;                       // [h][i] flat
    ((float2*)(ws + OFF_MS1T))[t] = make_float2(muW1[t], expf(vW1[t]));
  } else if (bb < 2560) {
    int t = (bb - 2048) * 256 + tid;              // [o][h] flat
    ((float2*)(ws + OFF_MS2T))[t] = make_float2(muW2[t], expf(vW2[t]));
  } else if (bb < 2688) {
    int t = (bb - 2560) * 256 + tid;              // x fragments, B-operand order
    int j = t & 7, lane = (t >> 3) & 63, fidx = t >> 9;
    int s = fidx >> 1, f = fidx & 1;
    int b = f * 16 + (lane & 15);
    int k = s * 32 + ((lane >> 4) << 3) + j;
    ((__bf16*)(ws + OFF_XF))[t] = (__bf16)x[b * D_IN + k];
  } else if (bb < 2988) {
    int t = (bb - 2688) * 256 + tid;              // b1s
    int h = t & 511;
    float eps = tf_normal(kb1_0, kb1_1, (uint32_t)t);
    ws[OFF_B1S + t] = fmaf(eps, expf(vb1[h]), mub1[h]);
  } else {
    int t = (bb - 2988) * 256 + tid;              // b2s
    int o = t & 255;
    float eps = tf_normal(kb2_0, kb2_1, (uint32_t)t);
    ws[OFF_B2S + t] = fmaf(eps, expf(vb2[o]), mub2[o]);
  }
}

// ---------- layer 1: K-split 2, 9600 waves; full asm RNG+transform ----------
__global__ __launch_bounds__(256) void l1_kernel(
    const float* __restrict__ ws, uint32_t k0, uint32_t k1) {
  const float2* __restrict__ ms1 = (const float2*)(ws + OFF_MS1T);
  const bf16x8* __restrict__ xf = (const bf16x8*)(ws + OFF_XF);
  const float* __restrict__ b1s = ws + OFF_B1S;
  __bf16* __restrict__ hB = (__bf16*)(ws + OFF_HB);
  uint32_t k2 = k0 ^ k1 ^ 0x1BD11BDAu;

  __shared__ f32x4 lred[2][2][64];   // 4096 B

  int lane = threadIdx.x & 63;
  int wib = threadIdx.x >> 6;
  int pairIdx = wib >> 1, khalf = wib & 1;
  int tile = blockIdx.x * 2 + pairIdx;   // 0..4799
  int n = tile >> 5;
  int ht = tile & 31;
  int mrow = lane & 15, quad = lane >> 4;
  int h = ht * 16 + mrow;
  uint32_t base = ((uint32_t)(n * 512 + h)) << 10;
  const float2* __restrict__ msrow = ms1 + (size_t)h * D_IN;

  f32x4 acc0 = {0.f, 0.f, 0.f, 0.f}, acc1 = {0.f, 0.f, 0.f, 0.f};

  int send = khalf * 16 + 16;
  for (int s = khalf * 16; s < send; ++s) {
    int kq = s * 32 + quad * 8;
    const f32x4* msq = (const f32x4*)(msrow + kq);
    f32x4 q0 = msq[0], q1 = msq[1], q2 = msq[2], q3 = msq[3];
    bf16x8 b0 = xf[(s * 2 + 0) * 64 + lane];
    bf16x8 b1 = xf[(s * 2 + 1) * 64 + lane];
    float eps[8];
    tf8_eps(k0, k1, k2, base + (uint32_t)kq, eps);
    float mu[8], sd[8];
    mu[0]=q0[0]; sd[0]=q0[1]; mu[1]=q0[2]; sd[1]=q0[3];
    mu[2]=q1[0]; sd[2]=q1[1]; mu[3]=q1[2]; sd[3]=q1[3];
    mu[4]=q2[0]; sd[4]=q2[1]; mu[5]=q2[2]; sd[5]=q2[3];
    mu[6]=q3[0]; sd[6]=q3[1]; mu[7]=q3[2]; sd[7]=q3[3];
    bf16x8 a;
#pragma unroll
    for (int j = 0; j < 8; ++j) a[j] = (__bf16)fmaf(eps[j], sd[j], mu[j]);
    acc0 = __builtin_amdgcn_mfma_f32_16x16x32_bf16(a, b0, acc0, 0, 0, 0);
    acc1 = __builtin_amdgcn_mfma_f32_16x16x32_bf16(a, b1, acc1, 0, 0, 0);
  }

  if (khalf) {
    lred[pairIdx][0][lane] = acc0;
    lred[pairIdx][1][lane] = acc1;
  }
  __syncthreads();
  if (!khalf) {
    f32x4 r0 = lred[pairIdx][0][lane], r1 = lred[pairIdx][1][lane];
    acc0 += r0; acc1 += r1;
    int hq = ht * 16 + quad * 4;
    float4 bias = *(const float4*)(b1s + n * 512 + hq);
    float bv[4] = {bias.x, bias.y, bias.z, bias.w};
    union { __bf16 v[4]; uint2 u; } p0, p1;
#pragma unroll
    for (int r = 0; r < 4; ++r) {
      p0.v[r] = (__bf16)fmaxf(acc0[r] + bv[r], 0.0f);
      p1.v[r] = (__bf16)fmaxf(acc1[r] + bv[r], 0.0f);
    }
    *(uint2*)(hB + ((size_t)(n * 32 + mrow) * 512 + hq)) = p0.u;
    *(uint2*)(hB + ((size_t)(n * 32 + 16 + mrow) * 512 + hq)) = p1.u;
  }
}

// ---------- layer 2: K-split 4, 9600 waves ----------
__global__ __launch_bounds__(256) void l2_kernel(
    const float* __restrict__ ws, float* __restrict__ y,
    uint32_t k0, uint32_t k1) {
  const float2* __restrict__ ms2 = (const float2*)(ws + OFF_MS2T);
  const bf16x8* __restrict__ hB8 = (const bf16x8*)(ws + OFF_HB);
  const float* __restrict__ b2s = ws + OFF_B2S;
  uint32_t k2 = k0 ^ k1 ^ 0x1BD11BDAu;

  __shared__ f32x4 lred[3][2][64];   // 6144 B

  int lane = threadIdx.x & 63;
  int wib = threadIdx.x >> 6;        // k-quarter 0..3
  int tile = blockIdx.x;             // 0..2399
  int n = tile >> 4;
  int ot = tile & 15;
  int mrow = lane & 15, quad = lane >> 4;
  int o = ot * 16 + mrow;
  uint32_t base = (uint32_t)(n * 256 + o) << 9;
  const float2* __restrict__ msrow = ms2 + (size_t)o * D_H;

  f32x4 acc0 = {0.f, 0.f, 0.f, 0.f}, acc1 = {0.f, 0.f, 0.f, 0.f};

  int send = wib * 4 + 4;
  for (int s = wib * 4; s < send; ++s) {
    int kq = s * 32 + quad * 8;
    const f32x4* msq = (const f32x4*)(msrow + kq);
    f32x4 q0 = msq[0], q1 = msq[1], q2 = msq[2], q3 = msq[3];
    bf16x8 b0 = hB8[(size_t)(n * 32 + mrow) * 64 + s * 4 + quad];
    bf16x8 b1 = hB8[(size_t)(n * 32 + 16 + mrow) * 64 + s * 4 + quad];
    float eps[8];
    tf8_eps(k0, k1, k2, base + (uint32_t)kq, eps);
    float mu[8], sd[8];
    mu[0]=q0[0]; sd[0]=q0[1]; mu[1]=q0[2]; sd[1]=q0[3];
    mu[2]=q1[0]; sd[2]=q1[1]; mu[3]=q1[2]; sd[3]=q1[3];
    mu[4]=q2[0]; sd[4]=q2[1]; mu[5]=q2[2]; sd[5]=q2[3];
    mu[6]=q3[0]; sd[6]=q3[1]; mu[7]=q3[2]; sd[7]=q3[3];
    bf16x8 a;
#pragma unroll
    for (int j = 0; j < 8; ++j) a[j] = (__bf16)fmaf(eps[j], sd[j], mu[j]);
    acc0 = __builtin_amdgcn_mfma_f32_16x16x32_bf16(a, b0, acc0, 0, 0, 0);
    acc1 = __builtin_amdgcn_mfma_f32_16x16x32_bf16(a, b1, acc1, 0, 0, 0);
  }

  if (wib) {
    lred[wib - 1][0][lane] = acc0;
    lred[wib - 1][1][lane] = acc1;
  }
  __syncthreads();
  if (!wib) {
#pragma unroll
    for (int c = 0; c < 3; ++c) {
      acc0 += lred[c][0][lane];
      acc1 += lred[c][1][lane];
    }
    int oq = ot * 16 + quad * 4;
    float4 bias = *(const float4*)(b2s + n * 256 + oq);
    float4 o0, o1;
    o0.x = acc0[0] + bias.x; o0.y = acc0[1] + bias.y;
    o0.z = acc0[2] + bias.z; o0.w = acc0[3] + bias.w;
    o1.x = acc1[0] + bias.x; o1.y = acc1[1] + bias.y;
    o1.z = acc1[2] + bias.z; o1.w = acc1[3] + bias.w;
    *(float4*)(y + (size_t)(n * 32 + mrow) * 256 + oq) = o0;
    *(float4*)(y + (size_t)(n * 32 + 16 + mrow) * 256 + oq) = o1;
  }
}

extern "C" void kernel_launch(void* const* d_in, const int* in_sizes, int n_in,
                              void* d_out, int out_size, void* d_ws, size_t ws_size,
                              hipStream_t stream) {
  const float* x = (const float*)d_in[0];
  const float* muW1 = (const float*)d_in[1];
  const float* mub1 = (const float*)d_in[2];
  const float* muW2 = (const float*)d_in[3];
  const float* mub2 = (const float*)d_in[4];
  const float* vW1 = (const float*)d_in[5];
  const float* vb1 = (const float*)d_in[6];
  const float* vW2 = (const float*)d_in[7];
  const float* vb2 = (const float*)d_in[8];
  float* y = (float*)d_out;
  float* ws = (float*)d_ws;

  uint32_t nk[4][2];
  for (uint32_t j = 0; j < 4; ++j) {
    threefry2x32(0u, 42u, 0u, j, nk[j][0], nk[j][1]);
  }
  // eW1=nk[0], eb1=nk[1], eW2=nk[2], eb2=nk[3]

  prep_kernel<<<3138, 256, 0, stream>>>(
      x, muW1, vW1, muW2, vW2, mub1, vb1, mub2, vb2, ws,
      nk[1][0], nk[1][1], nk[3][0], nk[3][1]);

  // l1: 4800 tiles x 2 k-halves = 9600 waves -> 2400 blocks x 256
  l1_kernel<<<2400, 256, 0, stream>>>(ws, nk[0][0], nk[0][1]);

  // l2: 2400 tiles x 4 k-quarters = 9600 waves -> 2400 blocks x 256
  l2_kernel<<<2400, 256, 0, stream>>>(ws, y, nk[2][0], nk[2][1]);
}

// Round 14
// 314.655 us; speedup vs baseline: 1.0246x; 1.0246x over previous
//
#include <hip/hip_runtime.h>
#include <stdint.h>

#define NS 150
#define D_IN 1024
#define D_H 512
#define D_OUT 256

typedef __bf16 bf16x8 __attribute__((ext_vector_type(8)));
typedef float f32x4 __attribute__((ext_vector_type(4)));

// ---- workspace layout (float offsets) ----
#define OFF_XF    0u          // x fragments, 32768 bf16 (MFMA B-operand order)
#define OFF_MS1T  16384u      // float2[512*1024] (mu,std) at [h][i]
#define OFF_MS2T  1064960u    // float2[256*512]  (mu,std) at [o][h]
#define OFF_B1S   1327104u    // 150*512 = 76800
#define OFF_B2S   1403904u    // 150*256 = 38400
#define OFF_HB    1442304u    // h bf16 [n][b][h]: 150*32*512 bf16

// sqrt(2)-folded ErfInv coefficients
#define SQ2 1.41421354f
#define CM0 (SQ2 * 2.81022636e-08f)
#define CM1 (SQ2 * 3.43273939e-07f)
#define CM2 (SQ2 * -3.5233877e-06f)
#define CM3 (SQ2 * -4.39150654e-06f)
#define CM4 (SQ2 * 0.00021858087f)
#define CM5 (SQ2 * -0.00125372503f)
#define CM6 (SQ2 * -0.00417768164f)
#define CM7 (SQ2 * 0.246640727f)
#define CM8 (SQ2 * 1.50140941f)
#define CT0 (SQ2 * -0.000200214257f)
#define CT1 (SQ2 * 0.000100950558f)
#define CT2 (SQ2 * 0.00134934322f)
#define CT3 (SQ2 * -0.00367342844f)
#define CT4 (SQ2 * 0.00573950773f)
#define CT5 (SQ2 * -0.0076224613f)
#define CT6 (SQ2 * 0.00943887047f)
#define CT7 (SQ2 * 1.00167406f)
#define CT8 (SQ2 * 2.83297682f)

// ---------- threefry-2x32 (JAX-exact, 20 rounds) ----------
#define ROTL32(x, r) __builtin_rotateleft32((x), (r))

__host__ __device__ __forceinline__ void threefry2x32(uint32_t k0, uint32_t k1,
                                                      uint32_t x0, uint32_t x1,
                                                      uint32_t& o0, uint32_t& o1) {
  uint32_t k2 = k0 ^ k1 ^ 0x1BD11BDAu;
  x0 += k0; x1 += k1;
#define TFR(r) { x0 += x1; x1 = ROTL32(x1, r); x1 ^= x0; }
  TFR(13) TFR(15) TFR(26) TFR(6)
  x0 += k1; x1 += k2 + 1u;
  TFR(17) TFR(29) TFR(16) TFR(24)
  x0 += k2; x1 += k0 + 2u;
  TFR(13) TFR(15) TFR(26) TFR(6)
  x0 += k0; x1 += k1 + 3u;
  TFR(17) TFR(29) TFR(16) TFR(24)
  x0 += k1; x1 += k2 + 4u;
  TFR(13) TFR(15) TFR(26) TFR(6)
  x0 += k2; x1 += k0 + 5u;
#undef TFR
  o0 = x0; o1 = x1;
}

// scalar path (prep biases only)
__device__ __forceinline__ float tf_normal(uint32_t k0, uint32_t k1, uint32_t idx) {
  uint32_t o0, o1;
  threefry2x32(k0, k1, 0u, idx, o0, o1);
  uint32_t bits = o0 ^ o1;
  uint32_t fb = (bits >> 9) | 0x3F800000u;
  float m = __uint_as_float(fb);
  const float lo = -0.99999994f;
  float u = fmaxf(fmaf(m, 2.0f, -3.0f), lo);
  float t = fmaf(u, -u, 1.0f);
  float w = -0.69314718056f * __builtin_amdgcn_logf(t);
  float p;
  if (w < 5.0f) {
    float ww = w - 2.5f;
    p = CM0;
    p = fmaf(p, ww, CM1); p = fmaf(p, ww, CM2); p = fmaf(p, ww, CM3);
    p = fmaf(p, ww, CM4); p = fmaf(p, ww, CM5); p = fmaf(p, ww, CM6);
    p = fmaf(p, ww, CM7); p = fmaf(p, ww, CM8);
  } else {
    float ww = __builtin_amdgcn_sqrtf(w) - 3.0f;
    p = CT0;
    p = fmaf(p, ww, CT1); p = fmaf(p, ww, CT2); p = fmaf(p, ww, CT3);
    p = fmaf(p, ww, CT4); p = fmaf(p, ww, CT5); p = fmaf(p, ww, CT6);
    p = fmaf(p, ww, CT7); p = fmaf(p, ww, CT8);
  }
  return p * u;
}

// ---------- 8-chain threefry: INLINE ASM (R12, proven: 248->206us) ----------
#define TF_ADD8 \
  "v_add_u32 %[a0], %[a0], %[b0]\n\t" "v_add_u32 %[a1], %[a1], %[b1]\n\t" \
  "v_add_u32 %[a2], %[a2], %[b2]\n\t" "v_add_u32 %[a3], %[a3], %[b3]\n\t" \
  "v_add_u32 %[a4], %[a4], %[b4]\n\t" "v_add_u32 %[a5], %[a5], %[b5]\n\t" \
  "v_add_u32 %[a6], %[a6], %[b6]\n\t" "v_add_u32 %[a7], %[a7], %[b7]\n\t"
#define TF_ROT8(sh) \
  "v_alignbit_b32 %[b0], %[b0], %[b0], " sh "\n\t" \
  "v_alignbit_b32 %[b1], %[b1], %[b1], " sh "\n\t" \
  "v_alignbit_b32 %[b2], %[b2], %[b2], " sh "\n\t" \
  "v_alignbit_b32 %[b3], %[b3], %[b3], " sh "\n\t" \
  "v_alignbit_b32 %[b4], %[b4], %[b4], " sh "\n\t" \
  "v_alignbit_b32 %[b5], %[b5], %[b5], " sh "\n\t" \
  "v_alignbit_b32 %[b6], %[b6], %[b6], " sh "\n\t" \
  "v_alignbit_b32 %[b7], %[b7], %[b7], " sh "\n\t"
#define TF_XOR8 \
  "v_xor_b32 %[b0], %[b0], %[a0]\n\t" "v_xor_b32 %[b1], %[b1], %[a1]\n\t" \
  "v_xor_b32 %[b2], %[b2], %[a2]\n\t" "v_xor_b32 %[b3], %[b3], %[a3]\n\t" \
  "v_xor_b32 %[b4], %[b4], %[a4]\n\t" "v_xor_b32 %[b5], %[b5], %[a5]\n\t" \
  "v_xor_b32 %[b6], %[b6], %[a6]\n\t" "v_xor_b32 %[b7], %[b7], %[a7]\n\t"
#define TF_ROUND(sh) TF_ADD8 TF_ROT8(sh) TF_XOR8
#define TF_INJ(KA, KB) \
  "v_add_u32 %[a0], " KA ", %[a0]\n\t" "v_add_u32 %[a1], " KA ", %[a1]\n\t" \
  "v_add_u32 %[a2], " KA ", %[a2]\n\t" "v_add_u32 %[a3], " KA ", %[a3]\n\t" \
  "v_add_u32 %[a4], " KA ", %[a4]\n\t" "v_add_u32 %[a5], " KA ", %[a5]\n\t" \
  "v_add_u32 %[a6], " KA ", %[a6]\n\t" "v_add_u32 %[a7], " KA ", %[a7]\n\t" \
  "v_add_u32 %[b0], " KB ", %[b0]\n\t" "v_add_u32 %[b1], " KB ", %[b1]\n\t" \
  "v_add_u32 %[b2], " KB ", %[b2]\n\t" "v_add_u32 %[b3], " KB ", %[b3]\n\t" \
  "v_add_u32 %[b4], " KB ", %[b4]\n\t" "v_add_u32 %[b5], " KB ", %[b5]\n\t" \
  "v_add_u32 %[b6], " KB ", %[b6]\n\t" "v_add_u32 %[b7], " KB ", %[b7]\n\t"

__device__ __forceinline__ void tf8_bits(uint32_t k0, uint32_t k1, uint32_t k2,
                                         uint32_t idx0, uint32_t* bits) {
  uint32_t k2p1 = k2 + 1u, k0p2 = k0 + 2u, k1p3 = k1 + 3u;
  uint32_t k2p4 = k2 + 4u, k0p5 = k0 + 5u;
  uint32_t t0 = idx0 + k1;
  uint32_t a0 = k0, a1 = k0, a2 = k0, a3 = k0, a4 = k0, a5 = k0, a6 = k0, a7 = k0;
  uint32_t b0 = t0, b1 = t0 + 1u, b2 = t0 + 2u, b3 = t0 + 3u;
  uint32_t b4 = t0 + 4u, b5 = t0 + 5u, b6 = t0 + 6u, b7 = t0 + 7u;
  asm(TF_ROUND("19") TF_ROUND("17") TF_ROUND("6") TF_ROUND("26")
      TF_INJ("%[k1]", "%[k2p1]")
      TF_ROUND("15") TF_ROUND("3") TF_ROUND("16") TF_ROUND("8")
      TF_INJ("%[k2]", "%[k0p2]")
      TF_ROUND("19") TF_ROUND("17") TF_ROUND("6") TF_ROUND("26")
      TF_INJ("%[k0]", "%[k1p3]")
      TF_ROUND("15") TF_ROUND("3") TF_ROUND("16") TF_ROUND("8")
      TF_INJ("%[k1]", "%[k2p4]")
      TF_ROUND("19") TF_ROUND("17") TF_ROUND("6") TF_ROUND("26")
      TF_INJ("%[k2]", "%[k0p5]")
      : [a0]"+v"(a0), [a1]"+v"(a1), [a2]"+v"(a2), [a3]"+v"(a3),
        [a4]"+v"(a4), [a5]"+v"(a5), [a6]"+v"(a6), [a7]"+v"(a7),
        [b0]"+v"(b0), [b1]"+v"(b1), [b2]"+v"(b2), [b3]"+v"(b3),
        [b4]"+v"(b4), [b5]"+v"(b5), [b6]"+v"(b6), [b7]"+v"(b7)
      : [k0]"s"(k0), [k1]"s"(k1), [k2]"s"(k2), [k2p1]"s"(k2p1),
        [k0p2]"s"(k0p2), [k1p3]"s"(k1p3), [k2p4]"s"(k2p4), [k0p5]"s"(k0p5));
  bits[0] = a0 ^ b0; bits[1] = a1 ^ b1; bits[2] = a2 ^ b2; bits[3] = a3 ^ b3;
  bits[4] = a4 ^ b4; bits[5] = a5 ^ b5; bits[6] = a6 ^ b6; bits[7] = a7 ^ b7;
}

// ---------- transform: asm A (bits->u,w) + asm B (main Horner) + C tail ----------
// R13 lesson: branchless tail regressed (+19us) -- always-computed tail costs
// ~128 instr/k-step vs ~21 expected for the divergent version (P(any lane
// tail) ~ 19%). Keep the branch in C; keep the branch-free A/B in asm.
#define FOR8(M) M(0) M(1) M(2) M(3) M(4) M(5) M(6) M(7)
#define FOR4(M) M(0) M(1) M(2) M(3)

#define A_SHR(j) "v_lshrrev_b32 %[u" #j "], 9, %[b" #j "]\n\t"
#define A_OR(j)  "v_or_b32 %[u" #j "], 0x3f800000, %[u" #j "]\n\t"
#define A_FMA(j) "v_fma_f32 %[u" #j "], %[u" #j "], 2.0, %[cm3]\n\t"
#define A_MAX(j) "v_max_f32 %[u" #j "], %[clo], %[u" #j "]\n\t"
#define A_T(j)   "v_fma_f32 %[w" #j "], %[u" #j "], -%[u" #j "], 1.0\n\t"
#define A_LOG(j) "v_log_f32 %[w" #j "], %[w" #j "]\n\t"
#define A_MUL(j) "v_mul_f32 %[w" #j "], %[cln], %[w" #j "]\n\t"

#define B_ADD(j) "v_add_f32 %[a" #j "], 0xc0200000, %[w" #j "]\n\t"  /* w - 2.5 */
#define B_MOV(j) "v_mov_b32 %[p" #j "], %[c0]\n\t"
#define B_F(j,c) "v_fma_f32 %[p" #j "], %[p" #j "], %[a" #j "], %[c" #c "]\n\t"
#define B_FMA(c) B_F(0,c) B_F(1,c) B_F(2,c) B_F(3,c)

__device__ __forceinline__ void erf4_main(float w0, float w1, float w2, float w3,
                                          float& p0o, float& p1o, float& p2o, float& p3o) {
  float a0, a1, a2, a3, p0, p1, p2, p3;
  asm(FOR4(B_ADD) FOR4(B_MOV)
      B_FMA(1) B_FMA(2) B_FMA(3) B_FMA(4) B_FMA(5) B_FMA(6) B_FMA(7) B_FMA(8)
      : [a0]"=&v"(a0), [a1]"=&v"(a1), [a2]"=&v"(a2), [a3]"=&v"(a3),
        [p0]"=&v"(p0), [p1]"=&v"(p1), [p2]"=&v"(p2), [p3]"=&v"(p3)
      : [w0]"v"(w0), [w1]"v"(w1), [w2]"v"(w2), [w3]"v"(w3),
        [c0]"s"(CM0), [c1]"s"(CM1), [c2]"s"(CM2), [c3]"s"(CM3), [c4]"s"(CM4),
        [c5]"s"(CM5), [c6]"s"(CM6), [c7]"s"(CM7), [c8]"s"(CM8));
  p0o = p0; p1o = p1; p2o = p2; p3o = p3;
}

__device__ __forceinline__ void tf8_eps(uint32_t k0, uint32_t k1, uint32_t k2,
                                        uint32_t idx0, float* eps) {
  uint32_t bits[8];
  tf8_bits(k0, k1, k2, idx0, bits);
  float u0, u1, u2, u3, u4, u5, u6, u7;
  float w0, w1, w2, w3, w4, w5, w6, w7;
  asm(FOR8(A_SHR) FOR8(A_OR) FOR8(A_FMA) FOR8(A_MAX)
      FOR8(A_T) FOR8(A_LOG) FOR8(A_MUL)
      : [u0]"=&v"(u0), [u1]"=&v"(u1), [u2]"=&v"(u2), [u3]"=&v"(u3),
        [u4]"=&v"(u4), [u5]"=&v"(u5), [u6]"=&v"(u6), [u7]"=&v"(u7),
        [w0]"=&v"(w0), [w1]"=&v"(w1), [w2]"=&v"(w2), [w3]"=&v"(w3),
        [w4]"=&v"(w4), [w5]"=&v"(w5), [w6]"=&v"(w6), [w7]"=&v"(w7)
      : [b0]"v"(bits[0]), [b1]"v"(bits[1]), [b2]"v"(bits[2]), [b3]"v"(bits[3]),
        [b4]"v"(bits[4]), [b5]"v"(bits[5]), [b6]"v"(bits[6]), [b7]"v"(bits[7]),
        [cm3]"s"(-3.0f), [clo]"s"(-0.99999994f), [cln]"s"(-0.69314718056f));
  float p[8];
  erf4_main(w0, w1, w2, w3, p[0], p[1], p[2], p[3]);
  erf4_main(w4, w5, w6, w7, p[4], p[5], p[6], p[7]);
  float uu[8] = {u0, u1, u2, u3, u4, u5, u6, u7};
  float wv[8] = {w0, w1, w2, w3, w4, w5, w6, w7};
#pragma unroll
  for (int j = 0; j < 8; ++j) {
    if (wv[j] >= 5.0f) {               // rare (P(any lane) ~19%): exec-masked
      float ww = __builtin_amdgcn_sqrtf(wv[j]) - 3.0f;
      float q = CT0;
      q = fmaf(q, ww, CT1); q = fmaf(q, ww, CT2); q = fmaf(q, ww, CT3);
      q = fmaf(q, ww, CT4); q = fmaf(q, ww, CT5); q = fmaf(q, ww, CT6);
      q = fmaf(q, ww, CT7); q = fmaf(q, ww, CT8);
      p[j] = q;
    }
    eps[j] = p[j] * uu[j];
  }
}

// ---------- prep ----------
__global__ __launch_bounds__(256) void prep_kernel(
    const float* __restrict__ x,
    const float* __restrict__ muW1, const float* __restrict__ vW1,
    const float* __restrict__ muW2, const float* __restrict__ vW2,
    const float* __restrict__ mub1, const float* __restrict__ vb1,
    const float* __restrict__ mub2, const float* __restrict__ vb2,
    float* __restrict__ ws,
    uint32_t kb1_0, uint32_t kb1_1, uint32_t kb2_0, uint32_t kb2_1) {
  int bb = blockIdx.x;
  int tid = threadIdx.x;
  if (bb < 2048) {
    int t = bb * 256 + tid;                       // [h][i] flat
    ((float2*)(ws + OFF_MS1T))[t] = make_float2(muW1[t], expf(vW1[t]));
  } else if (bb < 2560) {
    int t = (bb - 2048) * 256 + tid;              // [o][h] flat
    ((float2*)(ws + OFF_MS2T))[t] = make_float2(muW2[t], expf(vW2[t]));
  } else if (bb < 2688) {
    int t = (bb - 2560) * 256 + tid;              // x fragments, B-operand order
    int j = t & 7, lane = (t >> 3) & 63, fidx = t >> 9;
    int s = fidx >> 1, f = fidx & 1;
    int b = f * 16 + (lane & 15);
    int k = s * 32 + ((lane >> 4) << 3) + j;
    ((__bf16*)(ws + OFF_XF))[t] = (__bf16)x[b * D_IN + k];
  } else if (bb < 2988) {
    int t = (bb - 2688) * 256 + tid;              // b1s
    int h = t & 511;
    float eps = tf_normal(kb1_0, kb1_1, (uint32_t)t);
    ws[OFF_B1S + t] = fmaf(eps, expf(vb1[h]), mub1[h]);
  } else {
    int t = (bb - 2988) * 256 + tid;              // b2s
    int o = t & 255;
    float eps = tf_normal(kb2_0, kb2_1, (uint32_t)t);
    ws[OFF_B2S + t] = fmaf(eps, expf(vb2[o]), mub2[o]);
  }
}

// ---------- layer 1: K-split 2, 9600 waves ----------
__global__ __launch_bounds__(256) void l1_kernel(
    const float* __restrict__ ws, uint32_t k0, uint32_t k1) {
  const float2* __restrict__ ms1 = (const float2*)(ws + OFF_MS1T);
  const bf16x8* __restrict__ xf = (const bf16x8*)(ws + OFF_XF);
  const float* __restrict__ b1s = ws + OFF_B1S;
  __bf16* __restrict__ hB = (__bf16*)(ws + OFF_HB);
  uint32_t k2 = k0 ^ k1 ^ 0x1BD11BDAu;

  __shared__ f32x4 lred[2][2][64];   // 4096 B

  int lane = threadIdx.x & 63;
  int wib = threadIdx.x >> 6;
  int pairIdx = wib >> 1, khalf = wib & 1;
  int tile = blockIdx.x * 2 + pairIdx;   // 0..4799
  int n = tile >> 5;
  int ht = tile & 31;
  int mrow = lane & 15, quad = lane >> 4;
  int h = ht * 16 + mrow;
  uint32_t base = ((uint32_t)(n * 512 + h)) << 10;
  const float2* __restrict__ msrow = ms1 + (size_t)h * D_IN;

  f32x4 acc0 = {0.f, 0.f, 0.f, 0.f}, acc1 = {0.f, 0.f, 0.f, 0.f};

  int send = khalf * 16 + 16;
  for (int s = khalf * 16; s < send; ++s) {
    int kq = s * 32 + quad * 8;
    const f32x4* msq = (const f32x4*)(msrow + kq);
    f32x4 q0 = msq[0], q1 = msq[1], q2 = msq[2], q3 = msq[3];
    bf16x8 b0 = xf[(s * 2 + 0) * 64 + lane];
    bf16x8 b1 = xf[(s * 2 + 1) * 64 + lane];
    float eps[8];
    tf8_eps(k0, k1, k2, base + (uint32_t)kq, eps);
    float mu[8], sd[8];
    mu[0]=q0[0]; sd[0]=q0[1]; mu[1]=q0[2]; sd[1]=q0[3];
    mu[2]=q1[0]; sd[2]=q1[1]; mu[3]=q1[2]; sd[3]=q1[3];
    mu[4]=q2[0]; sd[4]=q2[1]; mu[5]=q2[2]; sd[5]=q2[3];
    mu[6]=q3[0]; sd[6]=q3[1]; mu[7]=q3[2]; sd[7]=q3[3];
    bf16x8 a;
#pragma unroll
    for (int j = 0; j < 8; ++j) a[j] = (__bf16)fmaf(eps[j], sd[j], mu[j]);
    acc0 = __builtin_amdgcn_mfma_f32_16x16x32_bf16(a, b0, acc0, 0, 0, 0);
    acc1 = __builtin_amdgcn_mfma_f32_16x16x32_bf16(a, b1, acc1, 0, 0, 0);
  }

  if (khalf) {
    lred[pairIdx][0][lane] = acc0;
    lred[pairIdx][1][lane] = acc1;
  }
  __syncthreads();
  if (!khalf) {
    f32x4 r0 = lred[pairIdx][0][lane], r1 = lred[pairIdx][1][lane];
    acc0 += r0; acc1 += r1;
    int hq = ht * 16 + quad * 4;
    float4 bias = *(const float4*)(b1s + n * 512 + hq);
    float bv[4] = {bias.x, bias.y, bias.z, bias.w};
    union { __bf16 v[4]; uint2 u; } p0, p1;
#pragma unroll
    for (int r = 0; r < 4; ++r) {
      p0.v[r] = (__bf16)fmaxf(acc0[r] + bv[r], 0.0f);
      p1.v[r] = (__bf16)fmaxf(acc1[r] + bv[r], 0.0f);
    }
    *(uint2*)(hB + ((size_t)(n * 32 + mrow) * 512 + hq)) = p0.u;
    *(uint2*)(hB + ((size_t)(n * 32 + 16 + mrow) * 512 + hq)) = p1.u;
  }
}

// ---------- layer 2: K-split 2 (was 4): 2 tiles x 2 khalves per block,
// 1200 blocks = 4800 waves (all resident, zero tail), epilogue cost halves ----------
__global__ __launch_bounds__(256) void l2_kernel(
    const float* __restrict__ ws, float* __restrict__ y,
    uint32_t k0, uint32_t k1) {
  const float2* __restrict__ ms2 = (const float2*)(ws + OFF_MS2T);
  const bf16x8* __restrict__ hB8 = (const bf16x8*)(ws + OFF_HB);
  const float* __restrict__ b2s = ws + OFF_B2S;
  uint32_t k2 = k0 ^ k1 ^ 0x1BD11BDAu;

  __shared__ f32x4 lred[2][2][64];   // 4096 B

  int lane = threadIdx.x & 63;
  int wib = threadIdx.x >> 6;
  int pairIdx = wib >> 1, khalf = wib & 1;
  int tile = blockIdx.x * 2 + pairIdx;   // 0..2399
  int n = tile >> 4;
  int ot = tile & 15;
  int mrow = lane & 15, quad = lane >> 4;
  int o = ot * 16 + mrow;
  uint32_t base = (uint32_t)(n * 256 + o) << 9;
  const float2* __restrict__ msrow = ms2 + (size_t)o * D_H;

  f32x4 acc0 = {0.f, 0.f, 0.f, 0.f}, acc1 = {0.f, 0.f, 0.f, 0.f};

  int send = khalf * 8 + 8;
  for (int s = khalf * 8; s < send; ++s) {
    int kq = s * 32 + quad * 8;
    const f32x4* msq = (const f32x4*)(msrow + kq);
    f32x4 q0 = msq[0], q1 = msq[1], q2 = msq[2], q3 = msq[3];
    bf16x8 b0 = hB8[(size_t)(n * 32 + mrow) * 64 + s * 4 + quad];
    bf16x8 b1 = hB8[(size_t)(n * 32 + 16 + mrow) * 64 + s * 4 + quad];
    float eps[8];
    tf8_eps(k0, k1, k2, base + (uint32_t)kq, eps);
    float mu[8], sd[8];
    mu[0]=q0[0]; sd[0]=q0[1]; mu[1]=q0[2]; sd[1]=q0[3];
    mu[2]=q1[0]; sd[2]=q1[1]; mu[3]=q1[2]; sd[3]=q1[3];
    mu[4]=q2[0]; sd[4]=q2[1]; mu[5]=q2[2]; sd[5]=q2[3];
    mu[6]=q3[0]; sd[6]=q3[1]; mu[7]=q3[2]; sd[7]=q3[3];
    bf16x8 a;
#pragma unroll
    for (int j = 0; j < 8; ++j) a[j] = (__bf16)fmaf(eps[j], sd[j], mu[j]);
    acc0 = __builtin_amdgcn_mfma_f32_16x16x32_bf16(a, b0, acc0, 0, 0, 0);
    acc1 = __builtin_amdgcn_mfma_f32_16x16x32_bf16(a, b1, acc1, 0, 0, 0);
  }

  if (khalf) {
    lred[pairIdx][0][lane] = acc0;
    lred[pairIdx][1][lane] = acc1;
  }
  __syncthreads();
  if (!khalf) {
    f32x4 r0 = lred[pairIdx][0][lane], r1 = lred[pairIdx][1][lane];
    acc0 += r0; acc1 += r1;
    int oq = ot * 16 + quad * 4;
    float4 bias = *(const float4*)(b2s + n * 256 + oq);
    float4 o0, o1;
    o0.x = acc0[0] + bias.x; o0.y = acc0[1] + bias.y;
    o0.z = acc0[2] + bias.z; o0.w = acc0[3] + bias.w;
    o1.x = acc1[0] + bias.x; o1.y = acc1[1] + bias.y;
    o1.z = acc1[2] + bias.z; o1.w = acc1[3] + bias.w;
    *(float4*)(y + (size_t)(n * 32 + mrow) * 256 + oq) = o0;
    *(float4*)(y + (size_t)(n * 32 + 16 + mrow) * 256 + oq) = o1;
  }
}

extern "C" void kernel_launch(void* const* d_in, const int* in_sizes, int n_in,
                              void* d_out, int out_size, void* d_ws, size_t ws_size,
                              hipStream_t stream) {
  const float* x = (const float*)d_in[0];
  const float* muW1 = (const float*)d_in[1];
  const float* mub1 = (const float*)d_in[2];
  const float* muW2 = (const float*)d_in[3];
  const float* mub2 = (const float*)d_in[4];
  const float* vW1 = (const float*)d_in[5];
  const float* vb1 = (const float*)d_in[6];
  const float* vW2 = (const float*)d_in[7];
  const float* vb2 = (const float*)d_in[8];
  float* y = (float*)d_out;
  float* ws = (float*)d_ws;

  uint32_t nk[4][2];
  for (uint32_t j = 0; j < 4; ++j) {
    threefry2x32(0u, 42u, 0u, j, nk[j][0], nk[j][1]);
  }
  // eW1=nk[0], eb1=nk[1], eW2=nk[2], eb2=nk[3]

  prep_kernel<<<3138, 256, 0, stream>>>(
      x, muW1, vW1, muW2, vW2, mub1, vb1, mub2, vb2, ws,
      nk[1][0], nk[1][1], nk[3][0], nk[3][1]);

  // l1: 4800 tiles x 2 k-halves = 9600 waves -> 2400 blocks x 256
  l1_kernel<<<2400, 256, 0, stream>>>(ws, nk[0][0], nk[0][1]);

  // l2: 2400 tiles x 2 k-halves = 4800 waves -> 1200 blocks x 256
  l2_kernel<<<1200, 256, 0, stream>>>(ws, y, nk[2][0], nk[2][1]);
}

// Round 15
// 297.819 us; speedup vs baseline: 1.0825x; 1.0565x over previous
//
#include <hip/hip_runtime.h>
#include <stdint.h>

#define NS 150
#define D_IN 1024
#define D_H 512
#define D_OUT 256

typedef __bf16 bf16x8 __attribute__((ext_vector_type(8)));
typedef float f32x4 __attribute__((ext_vector_type(4)));

// ---- workspace layout (float offsets) ----
#define OFF_XF    0u          // x fragments, 32768 bf16 (MFMA B-operand order)
#define OFF_MS1T  16384u      // float2[512*1024] (mu,std) at [h][i]
#define OFF_MS2T  1064960u    // float2[256*512]  (mu,std) at [o][h]
#define OFF_B1S   1327104u    // 150*512 = 76800
#define OFF_B2S   1403904u    // 150*256 = 38400
#define OFF_HB    1442304u    // h bf16 [n][b][h]: 150*32*512 bf16

// sqrt(2)-folded ErfInv coefficients (tail branch, exact 9-term)
#define SQ2 1.41421354f
#define CT0 (SQ2 * -0.000200214257f)
#define CT1 (SQ2 * 0.000100950558f)
#define CT2 (SQ2 * 0.00134934322f)
#define CT3 (SQ2 * -0.00367342844f)
#define CT4 (SQ2 * 0.00573950773f)
#define CT5 (SQ2 * -0.0076224613f)
#define CT6 (SQ2 * 0.00943887047f)
#define CT7 (SQ2 * 0.246640727f)   /* placeholder not used */
#define CM8 (SQ2 * 1.50140941f)

// Main-branch Horner re-based into z = log2(t) domain:
//   w = -ln2*z ; ww = w-2.5 = -ln2*(z + 2.5/ln2) ; coeffs folded by (-ln2)^k.
// Trimmed to 6 terms (dropped 2.8e-8/3.4e-7/3.5e-6 leading coeffs: poly err
// <=1.6e-3 on p -> <=3e-3 on output; budget 0.155, current 0.031).
#define DSQ2 1.4142135623730951
#define DA  (-0.6931471805599453)
#define ZC3 ((float)(DSQ2 * -4.39150654e-06 * DA*DA*DA*DA*DA))
#define ZC4 ((float)(DSQ2 * 0.00021858087   * DA*DA*DA*DA))
#define ZC5 ((float)(DSQ2 * -0.00125372503  * DA*DA*DA))
#define ZC6 ((float)(DSQ2 * -0.00417768164  * DA*DA))
#define ZC7 ((float)(DSQ2 * 0.246640727     * DA))
#define ZC8 ((float)(DSQ2 * 1.50140941))
#define ZSHIFT 3.6067376022224085f   /* 2.5/ln2 */
#define ZCUT  -7.213475204444817f    /* -(5/ln2): main branch iff z > ZCUT */

// Tail coeffs (exact, sqrt(2)-folded)
#define TT0 (SQ2 * -0.000200214257f)
#define TT1 (SQ2 * 0.000100950558f)
#define TT2 (SQ2 * 0.00134934322f)
#define TT3 (SQ2 * -0.00367342844f)
#define TT4 (SQ2 * 0.00573950773f)
#define TT5 (SQ2 * -0.0076224613f)
#define TT6 (SQ2 * 0.00943887047f)
#define TT7 (SQ2 * 1.00167406f)
#define TT8 (SQ2 * 2.83297682f)

// ---------- threefry-2x32 (JAX-exact, 20 rounds) ----------
#define ROTL32(x, r) __builtin_rotateleft32((x), (r))

__host__ __device__ __forceinline__ void threefry2x32(uint32_t k0, uint32_t k1,
                                                      uint32_t x0, uint32_t x1,
                                                      uint32_t& o0, uint32_t& o1) {
  uint32_t k2 = k0 ^ k1 ^ 0x1BD11BDAu;
  x0 += k0; x1 += k1;
#define TFR(r) { x0 += x1; x1 = ROTL32(x1, r); x1 ^= x0; }
  TFR(13) TFR(15) TFR(26) TFR(6)
  x0 += k1; x1 += k2 + 1u;
  TFR(17) TFR(29) TFR(16) TFR(24)
  x0 += k2; x1 += k0 + 2u;
  TFR(13) TFR(15) TFR(26) TFR(6)
  x0 += k0; x1 += k1 + 3u;
  TFR(17) TFR(29) TFR(16) TFR(24)
  x0 += k1; x1 += k2 + 4u;
  TFR(13) TFR(15) TFR(26) TFR(6)
  x0 += k2; x1 += k0 + 5u;
#undef TFR
  o0 = x0; o1 = x1;
}

// scalar path (prep biases only) — exact 9-term
__device__ __forceinline__ float tf_normal(uint32_t k0, uint32_t k1, uint32_t idx) {
  uint32_t o0, o1;
  threefry2x32(k0, k1, 0u, idx, o0, o1);
  uint32_t bits = o0 ^ o1;
  uint32_t fb = (bits >> 9) | 0x3F800000u;
  float m = __uint_as_float(fb);
  const float lo = -0.99999994f;
  float u = fmaxf(fmaf(m, 2.0f, -3.0f), lo);
  float t = fmaf(u, -u, 1.0f);
  float w = -0.69314718056f * __builtin_amdgcn_logf(t);
  float p;
  if (w < 5.0f) {
    float ww = w - 2.5f;
    p = SQ2 * 2.81022636e-08f;
    p = fmaf(p, ww, SQ2 * 3.43273939e-07f);
    p = fmaf(p, ww, SQ2 * -3.5233877e-06f);
    p = fmaf(p, ww, SQ2 * -4.39150654e-06f);
    p = fmaf(p, ww, SQ2 * 0.00021858087f);
    p = fmaf(p, ww, SQ2 * -0.00125372503f);
    p = fmaf(p, ww, SQ2 * -0.00417768164f);
    p = fmaf(p, ww, SQ2 * 0.246640727f);
    p = fmaf(p, ww, SQ2 * 1.50140941f);
  } else {
    float ww = __builtin_amdgcn_sqrtf(w) - 3.0f;
    p = TT0;
    p = fmaf(p, ww, TT1); p = fmaf(p, ww, TT2); p = fmaf(p, ww, TT3);
    p = fmaf(p, ww, TT4); p = fmaf(p, ww, TT5); p = fmaf(p, ww, TT6);
    p = fmaf(p, ww, TT7); p = fmaf(p, ww, TT8);
  }
  return p * u;
}

// ---------- 8-chain threefry: INLINE ASM (R12, proven) ----------
#define TF_ADD8 \
  "v_add_u32 %[a0], %[a0], %[b0]\n\t" "v_add_u32 %[a1], %[a1], %[b1]\n\t" \
  "v_add_u32 %[a2], %[a2], %[b2]\n\t" "v_add_u32 %[a3], %[a3], %[b3]\n\t" \
  "v_add_u32 %[a4], %[a4], %[b4]\n\t" "v_add_u32 %[a5], %[a5], %[b5]\n\t" \
  "v_add_u32 %[a6], %[a6], %[b6]\n\t" "v_add_u32 %[a7], %[a7], %[b7]\n\t"
#define TF_ROT8(sh) \
  "v_alignbit_b32 %[b0], %[b0], %[b0], " sh "\n\t" \
  "v_alignbit_b32 %[b1], %[b1], %[b1], " sh "\n\t" \
  "v_alignbit_b32 %[b2], %[b2], %[b2], " sh "\n\t" \
  "v_alignbit_b32 %[b3], %[b3], %[b3], " sh "\n\t" \
  "v_alignbit_b32 %[b4], %[b4], %[b4], " sh "\n\t" \
  "v_alignbit_b32 %[b5], %[b5], %[b5], " sh "\n\t" \
  "v_alignbit_b32 %[b6], %[b6], %[b6], " sh "\n\t" \
  "v_alignbit_b32 %[b7], %[b7], %[b7], " sh "\n\t"
#define TF_XOR8 \
  "v_xor_b32 %[b0], %[b0], %[a0]\n\t" "v_xor_b32 %[b1], %[b1], %[a1]\n\t" \
  "v_xor_b32 %[b2], %[b2], %[a2]\n\t" "v_xor_b32 %[b3], %[b3], %[a3]\n\t" \
  "v_xor_b32 %[b4], %[b4], %[a4]\n\t" "v_xor_b32 %[b5], %[b5], %[a5]\n\t" \
  "v_xor_b32 %[b6], %[b6], %[a6]\n\t" "v_xor_b32 %[b7], %[b7], %[a7]\n\t"
#define TF_ROUND(sh) TF_ADD8 TF_ROT8(sh) TF_XOR8
#define TF_INJ(KA, KB) \
  "v_add_u32 %[a0], " KA ", %[a0]\n\t" "v_add_u32 %[a1], " KA ", %[a1]\n\t" \
  "v_add_u32 %[a2], " KA ", %[a2]\n\t" "v_add_u32 %[a3], " KA ", %[a3]\n\t" \
  "v_add_u32 %[a4], " KA ", %[a4]\n\t" "v_add_u32 %[a5], " KA ", %[a5]\n\t" \
  "v_add_u32 %[a6], " KA ", %[a6]\n\t" "v_add_u32 %[a7], " KA ", %[a7]\n\t" \
  "v_add_u32 %[b0], " KB ", %[b0]\n\t" "v_add_u32 %[b1], " KB ", %[b1]\n\t" \
  "v_add_u32 %[b2], " KB ", %[b2]\n\t" "v_add_u32 %[b3], " KB ", %[b3]\n\t" \
  "v_add_u32 %[b4], " KB ", %[b4]\n\t" "v_add_u32 %[b5], " KB ", %[b5]\n\t" \
  "v_add_u32 %[b6], " KB ", %[b6]\n\t" "v_add_u32 %[b7], " KB ", %[b7]\n\t"

__device__ __forceinline__ void tf8_bits(uint32_t k0, uint32_t k1, uint32_t k2,
                                         uint32_t idx0, uint32_t* bits) {
  uint32_t k2p1 = k2 + 1u, k0p2 = k0 + 2u, k1p3 = k1 + 3u;
  uint32_t k2p4 = k2 + 4u, k0p5 = k0 + 5u;
  uint32_t t0 = idx0 + k1;
  uint32_t a0 = k0, a1 = k0, a2 = k0, a3 = k0, a4 = k0, a5 = k0, a6 = k0, a7 = k0;
  uint32_t b0 = t0, b1 = t0 + 1u, b2 = t0 + 2u, b3 = t0 + 3u;
  uint32_t b4 = t0 + 4u, b5 = t0 + 5u, b6 = t0 + 6u, b7 = t0 + 7u;
  asm(TF_ROUND("19") TF_ROUND("17") TF_ROUND("6") TF_ROUND("26")
      TF_INJ("%[k1]", "%[k2p1]")
      TF_ROUND("15") TF_ROUND("3") TF_ROUND("16") TF_ROUND("8")
      TF_INJ("%[k2]", "%[k0p2]")
      TF_ROUND("19") TF_ROUND("17") TF_ROUND("6") TF_ROUND("26")
      TF_INJ("%[k0]", "%[k1p3]")
      TF_ROUND("15") TF_ROUND("3") TF_ROUND("16") TF_ROUND("8")
      TF_INJ("%[k1]", "%[k2p4]")
      TF_ROUND("19") TF_ROUND("17") TF_ROUND("6") TF_ROUND("26")
      TF_INJ("%[k2]", "%[k0p5]")
      : [a0]"+v"(a0), [a1]"+v"(a1), [a2]"+v"(a2), [a3]"+v"(a3),
        [a4]"+v"(a4), [a5]"+v"(a5), [a6]"+v"(a6), [a7]"+v"(a7),
        [b0]"+v"(b0), [b1]"+v"(b1), [b2]"+v"(b2), [b3]"+v"(b3),
        [b4]"+v"(b4), [b5]"+v"(b5), [b6]"+v"(b6), [b7]"+v"(b7)
      : [k0]"s"(k0), [k1]"s"(k1), [k2]"s"(k2), [k2p1]"s"(k2p1),
        [k0p2]"s"(k0p2), [k1p3]"s"(k1p3), [k2p4]"s"(k2p4), [k0p5]"s"(k0p5));
  bits[0] = a0 ^ b0; bits[1] = a1 ^ b1; bits[2] = a2 ^ b2; bits[3] = a3 ^ b3;
  bits[4] = a4 ^ b4; bits[5] = a5 ^ b5; bits[6] = a6 ^ b6; bits[7] = a7 ^ b7;
}

// ---------- transform: C code (compiler version measured best, R12 vs R13/R14),
// z-domain Horner (saves the -ln2 mul), 6-term main poly, exact rare tail ----------
__device__ __forceinline__ float bits_normal(uint32_t bits) {
  uint32_t fb = (bits >> 9) | 0x3F800000u;
  float m = __uint_as_float(fb);
  const float lo = -0.99999994f;
  float u = fmaxf(fmaf(m, 2.0f, -3.0f), lo);
  float t = fmaf(u, -u, 1.0f);
  float z = __builtin_amdgcn_logf(t);          // log2(t) <= 0
  float p;
  if (z > ZCUT) {                              // w < 5 (common)
    float zz = z + ZSHIFT;
    p = ZC3;
    p = fmaf(p, zz, ZC4); p = fmaf(p, zz, ZC5); p = fmaf(p, zz, ZC6);
    p = fmaf(p, zz, ZC7); p = fmaf(p, zz, ZC8);
  } else {                                     // rare tail: exact
    float w = -0.69314718056f * z;
    float ww = __builtin_amdgcn_sqrtf(w) - 3.0f;
    p = TT0;
    p = fmaf(p, ww, TT1); p = fmaf(p, ww, TT2); p = fmaf(p, ww, TT3);
    p = fmaf(p, ww, TT4); p = fmaf(p, ww, TT5); p = fmaf(p, ww, TT6);
    p = fmaf(p, ww, TT7); p = fmaf(p, ww, TT8);
  }
  return p * u;
}

// ---------- prep ----------
__global__ __launch_bounds__(256) void prep_kernel(
    const float* __restrict__ x,
    const float* __restrict__ muW1, const float* __restrict__ vW1,
    const float* __restrict__ muW2, const float* __restrict__ vW2,
    const float* __restrict__ mub1, const float* __restrict__ vb1,
    const float* __restrict__ mub2, const float* __restrict__ vb2,
    float* __restrict__ ws,
    uint32_t kb1_0, uint32_t kb1_1, uint32_t kb2_0, uint32_t kb2_1) {
  int bb = blockIdx.x;
  int tid = threadIdx.x;
  if (bb < 2048) {
    int t = bb * 256 + tid;                       // [h][i] flat
    ((float2*)(ws + OFF_MS1T))[t] = make_float2(muW1[t], expf(vW1[t]));
  } else if (bb < 2560) {
    int t = (bb - 2048) * 256 + tid;              // [o][h] flat
    ((float2*)(ws + OFF_MS2T))[t] = make_float2(muW2[t], expf(vW2[t]));
  } else if (bb < 2688) {
    int t = (bb - 2560) * 256 + tid;              // x fragments, B-operand order
    int j = t & 7, lane = (t >> 3) & 63, fidx = t >> 9;
    int s = fidx >> 1, f = fidx & 1;
    int b = f * 16 + (lane & 15);
    int k = s * 32 + ((lane >> 4) << 3) + j;
    ((__bf16*)(ws + OFF_XF))[t] = (__bf16)x[b * D_IN + k];
  } else if (bb < 2988) {
    int t = (bb - 2688) * 256 + tid;              // b1s
    int h = t & 511;
    float eps = tf_normal(kb1_0, kb1_1, (uint32_t)t);
    ws[OFF_B1S + t] = fmaf(eps, expf(vb1[h]), mub1[h]);
  } else {
    int t = (bb - 2988) * 256 + tid;              // b2s
    int o = t & 255;
    float eps = tf_normal(kb2_0, kb2_1, (uint32_t)t);
    ws[OFF_B2S + t] = fmaf(eps, expf(vb2[o]), mub2[o]);
  }
}

// ---------- layer 1: K-split 2, 9600 waves (R12 structure) ----------
__global__ __launch_bounds__(256) void l1_kernel(
    const float* __restrict__ ws, uint32_t k0, uint32_t k1) {
  const float2* __restrict__ ms1 = (const float2*)(ws + OFF_MS1T);
  const bf16x8* __restrict__ xf = (const bf16x8*)(ws + OFF_XF);
  const float* __restrict__ b1s = ws + OFF_B1S;
  __bf16* __restrict__ hB = (__bf16*)(ws + OFF_HB);
  uint32_t k2 = k0 ^ k1 ^ 0x1BD11BDAu;

  __shared__ f32x4 lred[2][2][64];   // 4096 B

  int lane = threadIdx.x & 63;
  int wib = threadIdx.x >> 6;
  int pairIdx = wib >> 1, khalf = wib & 1;
  int tile = blockIdx.x * 2 + pairIdx;   // 0..4799
  int n = tile >> 5;
  int ht = tile & 31;
  int mrow = lane & 15, quad = lane >> 4;
  int h = ht * 16 + mrow;
  uint32_t base = ((uint32_t)(n * 512 + h)) << 10;
  const float2* __restrict__ msrow = ms1 + (size_t)h * D_IN;

  f32x4 acc0 = {0.f, 0.f, 0.f, 0.f}, acc1 = {0.f, 0.f, 0.f, 0.f};

  int send = khalf * 16 + 16;
  for (int s = khalf * 16; s < send; ++s) {
    int kq = s * 32 + quad * 8;
    const f32x4* msq = (const f32x4*)(msrow + kq);
    f32x4 q0 = msq[0], q1 = msq[1], q2 = msq[2], q3 = msq[3];
    bf16x8 b0 = xf[(s * 2 + 0) * 64 + lane];
    bf16x8 b1 = xf[(s * 2 + 1) * 64 + lane];
    uint32_t bits[8];
    tf8_bits(k0, k1, k2, base + (uint32_t)kq, bits);
    float mu[8], sd[8];
    mu[0]=q0[0]; sd[0]=q0[1]; mu[1]=q0[2]; sd[1]=q0[3];
    mu[2]=q1[0]; sd[2]=q1[1]; mu[3]=q1[2]; sd[3]=q1[3];
    mu[4]=q2[0]; sd[4]=q2[1]; mu[5]=q2[2]; sd[5]=q2[3];
    mu[6]=q3[0]; sd[6]=q3[1]; mu[7]=q3[2]; sd[7]=q3[3];
    bf16x8 a;
#pragma unroll
    for (int j = 0; j < 8; ++j) {
      float eps = bits_normal(bits[j]);
      a[j] = (__bf16)fmaf(eps, sd[j], mu[j]);
    }
    acc0 = __builtin_amdgcn_mfma_f32_16x16x32_bf16(a, b0, acc0, 0, 0, 0);
    acc1 = __builtin_amdgcn_mfma_f32_16x16x32_bf16(a, b1, acc1, 0, 0, 0);
  }

  if (khalf) {
    lred[pairIdx][0][lane] = acc0;
    lred[pairIdx][1][lane] = acc1;
  }
  __syncthreads();
  if (!khalf) {
    f32x4 r0 = lred[pairIdx][0][lane], r1 = lred[pairIdx][1][lane];
    acc0 += r0; acc1 += r1;
    int hq = ht * 16 + quad * 4;
    float4 bias = *(const float4*)(b1s + n * 512 + hq);
    float bv[4] = {bias.x, bias.y, bias.z, bias.w};
    union { __bf16 v[4]; uint2 u; } p0, p1;
#pragma unroll
    for (int r = 0; r < 4; ++r) {
      p0.v[r] = (__bf16)fmaxf(acc0[r] + bv[r], 0.0f);
      p1.v[r] = (__bf16)fmaxf(acc1[r] + bv[r], 0.0f);
    }
    *(uint2*)(hB + ((size_t)(n * 32 + mrow) * 512 + hq)) = p0.u;
    *(uint2*)(hB + ((size_t)(n * 32 + 16 + mrow) * 512 + hq)) = p1.u;
  }
}

// ---------- layer 2: K-split 2 (8 k-steps/wave, better amortization than K4) ----------
__global__ __launch_bounds__(256) void l2_kernel(
    const float* __restrict__ ws, float* __restrict__ y,
    uint32_t k0, uint32_t k1) {
  const float2* __restrict__ ms2 = (const float2*)(ws + OFF_MS2T);
  const bf16x8* __restrict__ hB8 = (const bf16x8*)(ws + OFF_HB);
  const float* __restrict__ b2s = ws + OFF_B2S;
  uint32_t k2 = k0 ^ k1 ^ 0x1BD11BDAu;

  __shared__ f32x4 lred[2][2][64];   // 4096 B

  int lane = threadIdx.x & 63;
  int wib = threadIdx.x >> 6;
  int pairIdx = wib >> 1, khalf = wib & 1;
  int tile = blockIdx.x * 2 + pairIdx;   // 0..2399
  int n = tile >> 4;
  int ot = tile & 15;
  int mrow = lane & 15, quad = lane >> 4;
  int o = ot * 16 + mrow;
  uint32_t base = (uint32_t)(n * 256 + o) << 9;
  const float2* __restrict__ msrow = ms2 + (size_t)o * D_H;

  f32x4 acc0 = {0.f, 0.f, 0.f, 0.f}, acc1 = {0.f, 0.f, 0.f, 0.f};

  int send = khalf * 8 + 8;
  for (int s = khalf * 8; s < send; ++s) {
    int kq = s * 32 + quad * 8;
    const f32x4* msq = (const f32x4*)(msrow + kq);
    f32x4 q0 = msq[0], q1 = msq[1], q2 = msq[2], q3 = msq[3];
    bf16x8 b0 = hB8[(size_t)(n * 32 + mrow) * 64 + s * 4 + quad];
    bf16x8 b1 = hB8[(size_t)(n * 32 + 16 + mrow) * 64 + s * 4 + quad];
    uint32_t bits[8];
    tf8_bits(k0, k1, k2, base + (uint32_t)kq, bits);
    float mu[8], sd[8];
    mu[0]=q0[0]; sd[0]=q0[1]; mu[1]=q0[2]; sd[1]=q0[3];
    mu[2]=q1[0]; sd[2]=q1[1]; mu[3]=q1[2]; sd[3]=q1[3];
    mu[4]=q2[0]; sd[4]=q2[1]; mu[5]=q2[2]; sd[5]=q2[3];
    mu[6]=q3[0]; sd[6]=q3[1]; mu[7]=q3[2]; sd[7]=q3[3];
    bf16x8 a;
#pragma unroll
    for (int j = 0; j < 8; ++j) {
      float eps = bits_normal(bits[j]);
      a[j] = (__bf16)fmaf(eps, sd[j], mu[j]);
    }
    acc0 = __builtin_amdgcn_mfma_f32_16x16x32_bf16(a, b0, acc0, 0, 0, 0);
    acc1 = __builtin_amdgcn_mfma_f32_16x16x32_bf16(a, b1, acc1, 0, 0, 0);
  }

  if (khalf) {
    lred[pairIdx][0][lane] = acc0;
    lred[pairIdx][1][lane] = acc1;
  }
  __syncthreads();
  if (!khalf) {
    f32x4 r0 = lred[pairIdx][0][lane], r1 = lred[pairIdx][1][lane];
    acc0 += r0; acc1 += r1;
    int oq = ot * 16 + quad * 4;
    float4 bias = *(const float4*)(b2s + n * 256 + oq);
    float4 o0, o1;
    o0.x = acc0[0] + bias.x; o0.y = acc0[1] + bias.y;
    o0.z = acc0[2] + bias.z; o0.w = acc0[3] + bias.w;
    o1.x = acc1[0] + bias.x; o1.y = acc1[1] + bias.y;
    o1.z = acc1[2] + bias.z; o1.w = acc1[3] + bias.w;
    *(float4*)(y + (size_t)(n * 32 + mrow) * 256 + oq) = o0;
    *(float4*)(y + (size_t)(n * 32 + 16 + mrow) * 256 + oq) = o1;
  }
}

extern "C" void kernel_launch(void* const* d_in, const int* in_sizes, int n_in,
                              void* d_out, int out_size, void* d_ws, size_t ws_size,
                              hipStream_t stream) {
  const float* x = (const float*)d_in[0];
  const float* muW1 = (const float*)d_in[1];
  const float* mub1 = (const float*)d_in[2];
  const float* muW2 = (const float*)d_in[3];
  const float* mub2 = (const float*)d_in[4];
  const float* vW1 = (const float*)d_in[5];
  const float* vb1 = (const float*)d_in[6];
  const float* vW2 = (const float*)d_in[7];
  const float* vb2 = (const float*)d_in[8];
  float* y = (float*)d_out;
  float* ws = (float*)d_ws;

  uint32_t nk[4][2];
  for (uint32_t j = 0; j < 4; ++j) {
    threefry2x32(0u, 42u, 0u, j, nk[j][0], nk[j][1]);
  }
  // eW1=nk[0], eb1=nk[1], eW2=nk[2], eb2=nk[3]

  prep_kernel<<<3138, 256, 0, stream>>>(
      x, muW1, vW1, muW2, vW2, mub1, vb1, mub2, vb2, ws,
      nk[1][0], nk[1][1], nk[3][0], nk[3][1]);

  // l1: 4800 tiles x 2 k-halves = 9600 waves -> 2400 blocks x 256
  l1_kernel<<<2400, 256, 0, stream>>>(ws, nk[0][0], nk[0][1]);

  // l2: 2400 tiles x 2 k-halves = 4800 waves -> 1200 blocks x 256
  l2_kernel<<<1200, 256, 0, stream>>>(ws, y, nk[2][0], nk[2][1]);
}